// Round 1
// baseline (172.014 us; speedup 1.0000x reference)
//
#include <hip/hip_runtime.h>
#include <stdint.h>
#include <math.h>

// Problem constants
#define NN 8192     // graph nodes == GEMM K
#define HD 256      // hidden dim == GEMM N
#define BATCH 2048
#define KSPLIT 8
#define KCH (NN / KSPLIT)   // 1024 K per block
#define NDOT 384            // 3*128 conv dots

typedef __attribute__((ext_vector_type(8))) short bf16x8;
typedef __attribute__((ext_vector_type(4))) float f32x4;

static __device__ __forceinline__ uint16_t f2bf(float x) {
  union { float f; uint32_t u; } a; a.f = x;
  return (uint16_t)((a.u + 0x7FFFu + ((a.u >> 16) & 1u)) >> 16);
}
static __device__ __forceinline__ uint32_t pack_bf2(float x, float y) {
  union { float f; uint32_t u; } a, b; a.f = x; b.f = y;
  uint32_t ua = a.u + 0x7FFFu + ((a.u >> 16) & 1u);
  uint32_t ub = b.u + 0x7FFFu + ((b.u >> 16) & 1u);
  return (ua >> 16) | (ub & 0xFFFF0000u);
}

// ---------------------------------------------------------------- K0a:
// emb [8192][256] f32  ->  embT [256][8192] bf16 (LDS 64x64 transpose)
extern "C" __global__ void k_transpose_emb(const float* __restrict__ emb,
                                           uint16_t* __restrict__ embT) {
  __shared__ float ts[64][65];
  const int k0 = blockIdx.x * 64, h0 = blockIdx.y * 64, tid = threadIdx.x;
#pragma unroll
  for (int i = 0; i < 16; i++) {
    int e = i * 256 + tid;
    ts[e >> 6][e & 63] = emb[(size_t)(k0 + (e >> 6)) * HD + h0 + (e & 63)];
  }
  __syncthreads();
#pragma unroll
  for (int i = 0; i < 16; i++) {
    int e = i * 256 + tid;
    int hh = e >> 6, kk = e & 63;
    embT[(size_t)(h0 + hh) * NN + k0 + kk] = f2bf(ts[kk][hh]);
  }
}

// ---------------------------------------------------------------- K0b:
// pack conv weight slices into aligned W[384][512]:
//   row j<128   : k1[j,0,0,1:513]
//   row 128+c   : k2[c,0,1,1:513]
//   row 256+c   : k2[c,0,0,1:513]
extern "C" __global__ void k_pack_w(const float* __restrict__ k1,
                                    const float* __restrict__ k2,
                                    float* __restrict__ W) {
  int idx = blockIdx.x * 256 + threadIdx.x;   // 384*512 total
  int j = idx >> 9, k = idx & 511;
  float v;
  if (j < 128)      v = k1[j * 514 + 1 + k];
  else if (j < 256) v = k2[(j - 128) * 1028 + 515 + k];
  else              v = k2[(j - 256) * 1028 + 1 + k];
  W[idx] = v;
}

// ---------------------------------------------------------------- GEMM:
// Rp[kblk][row][col] (f32 partials), row<4096 gathers A[batch_x|batch_y],
// col<256. bf16 MFMA 16x16x32, tile 64x256, BK=32, grid = 64 mblk * 8 kblk.
extern "C" __global__ __launch_bounds__(256, 2)
void k_gemm(const float* __restrict__ A, const uint16_t* __restrict__ embT,
            const int* __restrict__ bx, const int* __restrict__ by,
            float* __restrict__ Rp) {
  __shared__ __align__(16) uint16_t Af[64][32];   // bf16 A tile (lane-linear writes)
  __shared__ __align__(16) uint16_t Bf[8192];     // frag-ordered B: [ci][lane][8] bf16
  __shared__ int ridx[64];
  const int tid = threadIdx.x;
  const int mblk = blockIdx.x & 63;
  const int kblk = blockIdx.x >> 6;
  if (tid < 64) {
    int gr = mblk * 64 + tid;
    ridx[tid] = (gr < BATCH) ? bx[gr] : by[gr - BATCH];
  }
  __syncthreads();
  const int arow = ridx[tid >> 2];
  const int wv = tid >> 6, l = tid & 63, g = l >> 4, l15 = l & 15;
  const float* apBase = A + (size_t)arow * NN + (tid & 3) * 8;
  f32x4 acc[4][4] = {};
  for (int ks = 0; ks < KCH / 32; ks++) {
    const int k0 = kblk * KCH + ks * 32;
    // global loads into regs (overlap with previous iteration's tail)
    float4 a0 = *(const float4*)(apBase + k0);
    float4 a1 = *(const float4*)(apBase + k0 + 4);
    uint4 bvs[4];
#pragma unroll
    for (int i = 0; i < 4; i++) {
      int u = tid + i * 256;
      int ci = u >> 6, ll = u & 63;
      int c = ci * 16 + (ll & 15), gg = ll >> 4;
      bvs[i] = *(const uint4*)(embT + (size_t)c * NN + k0 + gg * 8);
    }
    __syncthreads();   // previous compute done reading LDS
    uint4 av;
    av.x = pack_bf2(a0.x, a0.y); av.y = pack_bf2(a0.z, a0.w);
    av.z = pack_bf2(a1.x, a1.y); av.w = pack_bf2(a1.z, a1.w);
    *(uint4*)((char*)Af + tid * 16) = av;                 // byte addr = 16*tid
#pragma unroll
    for (int i = 0; i < 4; i++) ((uint4*)Bf)[tid + i * 256] = bvs[i];
    __syncthreads();
    bf16x8 af[4], bfr[4];
#pragma unroll
    for (int ri = 0; ri < 4; ri++)
      af[ri] = *(const bf16x8*)&Af[ri * 16 + l15][g * 8];
#pragma unroll
    for (int ci = 0; ci < 4; ci++)
      bfr[ci] = *(const bf16x8*)(Bf + ((size_t)(wv * 4 + ci) * 64 + l) * 8);
#pragma unroll
    for (int ri = 0; ri < 4; ri++)
#pragma unroll
      for (int ci = 0; ci < 4; ci++)
        acc[ri][ci] = __builtin_amdgcn_mfma_f32_16x16x32_bf16(
            af[ri], bfr[ci], acc[ri][ci], 0, 0, 0);
  }
  float* Rpk = Rp + (size_t)kblk * (4096 * HD);
#pragma unroll
  for (int ri = 0; ri < 4; ri++)
#pragma unroll
    for (int ci = 0; ci < 4; ci++)
#pragma unroll
      for (int r = 0; r < 4; r++)
        Rpk[(size_t)(mblk * 64 + ri * 16 + g * 4 + r) * HD +
            wv * 64 + ci * 16 + l15] = acc[ri][ci][r];
}

// ---------------------------------------------------------------- tail:
// 8 batch elems per block. t[512] per elem in LDS (t_s[k][bi]); 384 dots of
// 512 vs packed W; enc/score/log-softmax epilogue.
extern "C" __global__ __launch_bounds__(256, 2)
void k_tail(const float* __restrict__ Rp, const float* __restrict__ W,
            const float* __restrict__ b1, const float* __restrict__ b2,
            const float* __restrict__ dw, const float* __restrict__ dbias,
            float* __restrict__ out) {
  __shared__ float t_s[512][8];
  __shared__ float d_s[8][NDOT];
  const int tid = threadIdx.x;
  const int b0 = blockIdx.x * 8;
#pragma unroll
  for (int bi = 0; bi < 8; bi++) {
    const int b = b0 + bi;
    float rq = 0.f, ra = 0.f;
#pragma unroll
    for (int p = 0; p < KSPLIT; p++) {
      rq += Rp[((size_t)p * 4096 + b) * HD + tid];
      ra += Rp[((size_t)p * 4096 + BATCH + b) * HD + tid];
    }
    float d = rq - ra;
    t_s[tid][bi] = d * d;        // (rQ-rA)^2
    t_s[256 + tid][bi] = rq * ra; // rQ*rA
  }
  __syncthreads();
  {
    float acc[8] = {0, 0, 0, 0, 0, 0, 0, 0};
    const float* wr = W + (size_t)tid * 512;
#pragma unroll 4
    for (int k = 0; k < 512; k++) {
      float wk = wr[k];
#pragma unroll
      for (int bi = 0; bi < 8; bi++) acc[bi] += t_s[k][bi] * wk;
    }
#pragma unroll
    for (int bi = 0; bi < 8; bi++) d_s[bi][tid] = acc[bi];
  }
  if (tid < 128) {
    float acc[8] = {0, 0, 0, 0, 0, 0, 0, 0};
    const float* wr = W + (size_t)(256 + tid) * 512;
#pragma unroll 4
    for (int k = 0; k < 512; k++) {
      float wk = wr[k];
#pragma unroll
      for (int bi = 0; bi < 8; bi++) acc[bi] += t_s[k][bi] * wk;
    }
#pragma unroll
    for (int bi = 0; bi < 8; bi++) d_s[bi][256 + tid] = acc[bi];
  }
  __syncthreads();
  const int bi = tid >> 5, cb = (tid & 31) * 4;
  float s0 = 0.f, s1 = 0.f;
#pragma unroll
  for (int cc = 0; cc < 4; cc++) {
    const int c = cb + cc;
    float d1 = d_s[bi][c], d2a = d_s[bi][128 + c], d2b = d_s[bi][256 + c];
    float bb1 = b1[c], bb2 = b2[c];
    float e1 = fmaxf(0.f, fmaxf(bb1, d1 + bb1));          // max-pool over conv1 outputs
    float e2 = fmaxf(0.f, fmaxf(d2a + bb2, d2b + bb2));   // max-pool over conv2 outputs
    s0 += e1 * (dw[c] + dw[256 + c]) + e2 * (dw[128 + c] + dw[384 + c]);
    s1 += e1 * (dw[512 + c] + dw[768 + c]) + e2 * (dw[640 + c] + dw[896 + c]);
  }
#pragma unroll
  for (int off = 16; off >= 1; off >>= 1) {
    s0 += __shfl_xor(s0, off);
    s1 += __shfl_xor(s1, off);
  }
  if ((tid & 31) == 0) {
    s0 += dbias[0]; s1 += dbias[1];
    float m = fmaxf(s0, s1);
    float lse = m + logf(expf(s0 - m) + expf(s1 - m));
    out[(b0 + bi) * 2] = s0 - lse;
    out[(b0 + bi) * 2 + 1] = s1 - lse;
  }
}

// ---------------------------------------------------------------- launch
extern "C" void kernel_launch(void* const* d_in, const int* in_sizes, int n_in,
                              void* d_out, int out_size, void* d_ws, size_t ws_size,
                              hipStream_t stream) {
  const float* emb = (const float*)d_in[0];
  const float* A   = (const float*)d_in[1];
  const float* k1  = (const float*)d_in[2];
  const float* b1  = (const float*)d_in[3];
  const float* k2  = (const float*)d_in[4];
  const float* b2  = (const float*)d_in[5];
  const float* dw  = (const float*)d_in[6];
  const float* dbi = (const float*)d_in[7];
  const int* bx = (const int*)d_in[8];
  const int* by = (const int*)d_in[9];
  float* out = (float*)d_out;
  char* ws = (char*)d_ws;
  // ws layout: [0,4M) embT bf16 ; [4M,4.75M) packed W ; [8M,40M) Rp partials
  uint16_t* embT = (uint16_t*)ws;
  float* W  = (float*)(ws + (4u << 20));
  float* Rp = (float*)(ws + (8u << 20));

  k_transpose_emb<<<dim3(128, 4), 256, 0, stream>>>(emb, embT);
  k_pack_w<<<(NDOT * 512) / 256, 256, 0, stream>>>(k1, k2, W);
  k_gemm<<<64 * KSPLIT, 256, 0, stream>>>(A, embT, bx, by, Rp);
  k_tail<<<BATCH / 8, 256, 0, stream>>>(Rp, W, b1, b2, dw, dbi, out);
}

// Round 2
// 117.595 us; speedup vs baseline: 1.4628x; 1.4628x over previous
//
#include <hip/hip_runtime.h>
#include <stdint.h>
#include <math.h>

// Problem constants
#define NN 8192     // graph nodes == GEMM K
#define HD 256      // hidden dim == GEMM N
#define BATCH 2048
#define KSPLIT 8
#define KCH (NN / KSPLIT)   // 1024 K per (kblk) block
#define NDOT 384            // 3*128 conv dots

typedef __attribute__((ext_vector_type(8))) short bf16x8;
typedef __attribute__((ext_vector_type(4))) float f32x4;

static __device__ __forceinline__ uint16_t f2bf(float x) {
  union { float f; uint32_t u; } a; a.f = x;
  return (uint16_t)((a.u + 0x7FFFu + ((a.u >> 16) & 1u)) >> 16);
}
static __device__ __forceinline__ uint32_t pack_bf2(float x, float y) {
  union { float f; uint32_t u; } a, b; a.f = x; b.f = y;
  uint32_t ua = a.u + 0x7FFFu + ((a.u >> 16) & 1u);
  uint32_t ub = b.u + 0x7FFFu + ((b.u >> 16) & 1u);
  return (ua >> 16) | (ub & 0xFFFF0000u);
}

static __device__ __forceinline__ void gld_lds16(const void* g, void* l) {
  __builtin_amdgcn_global_load_lds(
      (const __attribute__((address_space(1))) void*)g,
      (__attribute__((address_space(3))) void*)l, 16, 0, 0);
}

// ---------------------------------------------------------------- prep A:
// gather batch rows of A, convert to bf16: Abf[4096][8192]
extern "C" __global__ void k_prep_a(const float* __restrict__ A,
                                    const int* __restrict__ bx,
                                    const int* __restrict__ by,
                                    uint16_t* __restrict__ Abf) {
  const int r = blockIdx.x;                    // 0..4095
  const int src = (r < BATCH) ? bx[r] : by[r - BATCH];
  const float* ap = A + (size_t)src * NN;
  uint16_t* op = Abf + (size_t)r * NN;
  const int tid = threadIdx.x;
#pragma unroll
  for (int i = 0; i < 4; i++) {
    int off = i * 2048 + tid * 8;
    float4 f0 = *(const float4*)(ap + off);
    float4 f1 = *(const float4*)(ap + off + 4);
    uint4 v;
    v.x = pack_bf2(f0.x, f0.y); v.y = pack_bf2(f0.z, f0.w);
    v.z = pack_bf2(f1.x, f1.y); v.w = pack_bf2(f1.z, f1.w);
    *(uint4*)(op + off) = v;
  }
}

// ---------------------------------------------------------------- make Bm:
// emb[8192][256] f32 -> Bm frag-major bf16:
// Bm[kc][ci][l][j] = emb[kc*32 + (l>>4)*8 + j][ci*16 + (l&15)]
// (kc = K-chunk of 32, ci = 16-col group, l = lane, j = 0..7)
extern "C" __global__ void k_make_bm(const float* __restrict__ emb,
                                     uint16_t* __restrict__ Bm) {
  __shared__ float ts[32][257];
  const int kc = blockIdx.x;                   // 0..255
  const int tid = threadIdx.x;
#pragma unroll
  for (int i = 0; i < 32; i++)
    ts[i][tid] = emb[(size_t)(kc * 32 + i) * HD + tid];
  __syncthreads();
#pragma unroll
  for (int c = 0; c < 4; c++) {
    int e = c * 256 + tid;                     // 16B-chunk index within kc (0..1023)
    int ci = e >> 6, l = e & 63;
    int g = l >> 4, col = ci * 16 + (l & 15);
    uint4 v;
    v.x = pack_bf2(ts[g * 8 + 0][col], ts[g * 8 + 1][col]);
    v.y = pack_bf2(ts[g * 8 + 2][col], ts[g * 8 + 3][col]);
    v.z = pack_bf2(ts[g * 8 + 4][col], ts[g * 8 + 5][col]);
    v.w = pack_bf2(ts[g * 8 + 6][col], ts[g * 8 + 7][col]);
    ((uint4*)Bm)[(size_t)kc * 1024 + e] = v;
  }
}

// ---------------------------------------------------------------- K0b:
// pack conv weight slices into aligned W[384][512]
extern "C" __global__ void k_pack_w(const float* __restrict__ k1,
                                    const float* __restrict__ k2,
                                    float* __restrict__ W) {
  int idx = blockIdx.x * 256 + threadIdx.x;    // 384*512 total
  int j = idx >> 9, k = idx & 511;
  float v;
  if (j < 128)      v = k1[j * 514 + 1 + k];
  else if (j < 256) v = k2[(j - 128) * 1028 + 515 + k];
  else              v = k2[(j - 256) * 1028 + 1 + k];
  W[idx] = v;
}

// ---------------------------------------------------------------- GEMM:
// Rp[kblk][row][col] f32 partials. Abf[4096][8192] bf16 x Bm frag-major.
// tile 64x256, BK=64, global_load_lds staging, XOR-swizzled A tile.
// grid: bid = mblk*8 + kblk  (round-robin XCD => xcd == kblk, B L2-resident)
extern "C" __global__ __launch_bounds__(256, 2)
void k_gemm(const uint16_t* __restrict__ Abf, const uint16_t* __restrict__ Bm,
            float* __restrict__ Rp) {
  __shared__ __align__(16) uint16_t Af[64 * 64];    // 8 KB  [row][k] swizzled
  __shared__ __align__(16) uint16_t Bf[2 * 8192];   // 32 KB two frag-major chunks
  const int tid = threadIdx.x;
  const int kblk = blockIdx.x & 7;
  const int mblk = blockIdx.x >> 3;
  const int wv = tid >> 6, l = tid & 63, g = l >> 4, l15 = l & 15;

  // staging geometry (constant per thread)
  const int arow0 = (0 * 256 + tid) >> 3, as0 = tid & 7;
  const int arow1 = (1 * 256 + tid) >> 3, as1 = tid & 7;   // rows 32..63
  const uint16_t* aSrc0 = Abf + (size_t)(mblk * 64 + arow0) * NN + ((as0 ^ (arow0 & 7)) << 3);
  const uint16_t* aSrc1 = Abf + (size_t)(mblk * 64 + arow1) * NN + ((as1 ^ (arow1 & 7)) << 3);
  uint16_t* aDst0 = Af + (size_t)(0 * 256 + wv * 64) * 8;
  uint16_t* aDst1 = Af + (size_t)(1 * 256 + wv * 64) * 8;

  f32x4 acc[4][4] = {};
  for (int ks = 0; ks < KCH / 64; ks++) {
    const int k0 = kblk * KCH + ks * 64;
    __syncthreads();                          // previous compute done reading LDS
    // A: 2 x 16B per thread (inverse-swizzled source, linear dest)
    gld_lds16(aSrc0 + k0, aDst0);
    gld_lds16(aSrc1 + k0, aDst1);
    // B: 8 x 16B per thread, pure linear copy of 2 frag-major chunks
    const uint16_t* bSrc = Bm + ((size_t)(k0 >> 5)) * 8192;
#pragma unroll
    for (int c = 0; c < 8; c++)
      gld_lds16(bSrc + (size_t)(c * 256 + tid) * 8,
                Bf + (size_t)(c * 256 + wv * 64) * 8);
    asm volatile("s_waitcnt vmcnt(0)" ::: "memory");
    __syncthreads();

    bf16x8 af[2][4], bfr[2][4];
#pragma unroll
    for (int kk = 0; kk < 2; kk++)
#pragma unroll
      for (int ri = 0; ri < 4; ri++)
        af[kk][ri] = *(const bf16x8*)(Af + (ri * 16 + l15) * 64 +
                                      (((kk * 4 + g) ^ (l15 & 7)) << 3));
#pragma unroll
    for (int kk = 0; kk < 2; kk++)
#pragma unroll
      for (int ci = 0; ci < 4; ci++)
        bfr[kk][ci] = *(const bf16x8*)(Bf + kk * 8192 +
                                       (size_t)((wv * 4 + ci) * 64 + l) * 8);
#pragma unroll
    for (int kk = 0; kk < 2; kk++)
#pragma unroll
      for (int ri = 0; ri < 4; ri++)
#pragma unroll
        for (int ci = 0; ci < 4; ci++)
          acc[ri][ci] = __builtin_amdgcn_mfma_f32_16x16x32_bf16(
              af[kk][ri], bfr[kk][ci], acc[ri][ci], 0, 0, 0);
  }
  float* Rpk = Rp + (size_t)kblk * (4096 * HD);
#pragma unroll
  for (int ri = 0; ri < 4; ri++)
#pragma unroll
    for (int ci = 0; ci < 4; ci++)
#pragma unroll
      for (int r = 0; r < 4; r++)
        Rpk[(size_t)(mblk * 64 + ri * 16 + g * 4 + r) * HD +
            wv * 64 + ci * 16 + l15] = acc[ri][ci][r];
}

// ---------------------------------------------------------------- tail:
// 8 batch elems per block. t[512] per elem in LDS; 384 dots of 512 vs W;
// enc/score/log-softmax epilogue.
extern "C" __global__ __launch_bounds__(256, 2)
void k_tail(const float* __restrict__ Rp, const float* __restrict__ W,
            const float* __restrict__ b1, const float* __restrict__ b2,
            const float* __restrict__ dw, const float* __restrict__ dbias,
            float* __restrict__ out) {
  __shared__ float t_s[512][9];     // pad 8->9: kills 16-way write conflict
  __shared__ float d_s[8][NDOT];
  const int tid = threadIdx.x;
  const int b0 = blockIdx.x * 8;
#pragma unroll
  for (int bi = 0; bi < 8; bi++) {
    const int b = b0 + bi;
    float rq = 0.f, ra = 0.f;
#pragma unroll
    for (int p = 0; p < KSPLIT; p++) {
      rq += Rp[((size_t)p * 4096 + b) * HD + tid];
      ra += Rp[((size_t)p * 4096 + BATCH + b) * HD + tid];
    }
    float d = rq - ra;
    t_s[tid][bi] = d * d;          // (rQ-rA)^2
    t_s[256 + tid][bi] = rq * ra;  // rQ*rA
  }
  __syncthreads();
  {
    float acc[8] = {0, 0, 0, 0, 0, 0, 0, 0};
    const float* wr = W + (size_t)tid * 512;
#pragma unroll 4
    for (int k = 0; k < 512; k++) {
      float wk = wr[k];
#pragma unroll
      for (int bi = 0; bi < 8; bi++) acc[bi] += t_s[k][bi] * wk;
    }
#pragma unroll
    for (int bi = 0; bi < 8; bi++) d_s[bi][tid] = acc[bi];
  }
  if (tid < 128) {
    float acc[8] = {0, 0, 0, 0, 0, 0, 0, 0};
    const float* wr = W + (size_t)(256 + tid) * 512;
#pragma unroll 4
    for (int k = 0; k < 512; k++) {
      float wk = wr[k];
#pragma unroll
      for (int bi = 0; bi < 8; bi++) acc[bi] += t_s[k][bi] * wk;
    }
#pragma unroll
    for (int bi = 0; bi < 8; bi++) d_s[bi][256 + tid] = acc[bi];
  }
  __syncthreads();
  const int bi = tid >> 5, cb = (tid & 31) * 4;
  float s0 = 0.f, s1 = 0.f;
#pragma unroll
  for (int cc = 0; cc < 4; cc++) {
    const int c = cb + cc;
    float d1 = d_s[bi][c], d2a = d_s[bi][128 + c], d2b = d_s[bi][256 + c];
    float bb1 = b1[c], bb2 = b2[c];
    float e1 = fmaxf(0.f, fmaxf(bb1, d1 + bb1));          // max-pool conv1
    float e2 = fmaxf(0.f, fmaxf(d2a + bb2, d2b + bb2));   // max-pool conv2
    s0 += e1 * (dw[c] + dw[256 + c]) + e2 * (dw[128 + c] + dw[384 + c]);
    s1 += e1 * (dw[512 + c] + dw[768 + c]) + e2 * (dw[640 + c] + dw[896 + c]);
  }
#pragma unroll
  for (int off = 16; off >= 1; off >>= 1) {
    s0 += __shfl_xor(s0, off);
    s1 += __shfl_xor(s1, off);
  }
  if ((tid & 31) == 0) {
    s0 += dbias[0]; s1 += dbias[1];
    float m = fmaxf(s0, s1);
    float lse = m + logf(expf(s0 - m) + expf(s1 - m));
    out[(b0 + bi) * 2] = s0 - lse;
    out[(b0 + bi) * 2 + 1] = s1 - lse;
  }
}

// ---------------------------------------------------------------- launch
extern "C" void kernel_launch(void* const* d_in, const int* in_sizes, int n_in,
                              void* d_out, int out_size, void* d_ws, size_t ws_size,
                              hipStream_t stream) {
  const float* emb = (const float*)d_in[0];
  const float* A   = (const float*)d_in[1];
  const float* k1  = (const float*)d_in[2];
  const float* b1  = (const float*)d_in[3];
  const float* k2  = (const float*)d_in[4];
  const float* b2  = (const float*)d_in[5];
  const float* dw  = (const float*)d_in[6];
  const float* dbi = (const float*)d_in[7];
  const int* bx = (const int*)d_in[8];
  const int* by = (const int*)d_in[9];
  float* out = (float*)d_out;
  char* ws = (char*)d_ws;
  // ws layout: [0,64M) Abf bf16 ; [64M,68M) Bm bf16 ; [68M,69M) W ;
  //            [72M,104M) Rp f32 partials
  uint16_t* Abf = (uint16_t*)ws;
  uint16_t* Bm  = (uint16_t*)(ws + (64u << 20));
  float* W  = (float*)(ws + (68u << 20));
  float* Rp = (float*)(ws + (72u << 20));

  k_prep_a<<<4096, 256, 0, stream>>>(A, bx, by, Abf);
  k_make_bm<<<256, 256, 0, stream>>>(emb, Bm);
  k_pack_w<<<(NDOT * 512) / 256, 256, 0, stream>>>(k1, k2, W);
  k_gemm<<<64 * KSPLIT, 256, 0, stream>>>(Abf, Bm, Rp);
  k_tail<<<BATCH / 8, 256, 0, stream>>>(Rp, W, b1, b2, dw, dbi, out);
}

// Round 3
// 100.165 us; speedup vs baseline: 1.7173x; 1.1740x over previous
//
#include <hip/hip_runtime.h>
#include <stdint.h>
#include <math.h>

// Problem constants
#define NN 8192     // graph nodes == GEMM K
#define HD 256      // hidden dim == GEMM N
#define BATCH 2048
#define KSPLIT 4
#define KCH (NN / KSPLIT)   // 2048 K per kblk
#define NDOT 384            // 3*128 conv dots

typedef __attribute__((ext_vector_type(8))) short bf16x8;
typedef __attribute__((ext_vector_type(4))) float f32x4;

static __device__ __forceinline__ uint16_t f2bf(float x) {
  union { float f; uint32_t u; } a; a.f = x;
  return (uint16_t)((a.u + 0x7FFFu + ((a.u >> 16) & 1u)) >> 16);
}
static __device__ __forceinline__ uint32_t pack_bf2(float x, float y) {
  union { float f; uint32_t u; } a, b; a.f = x; b.f = y;
  uint32_t ua = a.u + 0x7FFFu + ((a.u >> 16) & 1u);
  uint32_t ub = b.u + 0x7FFFu + ((b.u >> 16) & 1u);
  return (ua >> 16) | (ub & 0xFFFF0000u);
}
static __device__ __forceinline__ float bf_lo(uint32_t u) {
  return __uint_as_float(u << 16);
}
static __device__ __forceinline__ float bf_hi(uint32_t u) {
  return __uint_as_float(u & 0xFFFF0000u);
}
static __device__ __forceinline__ void gld_lds16(const void* g, void* l) {
  __builtin_amdgcn_global_load_lds(
      (const __attribute__((address_space(1))) void*)g,
      (__attribute__((address_space(3))) void*)l, 16, 0, 0);
}

// ---------------------------------------------------------------- make Bm:
// emb[8192][256] f32 -> Bm frag-major bf16:
// Bm[kc][ci][l][j] = emb[kc*32 + (l>>4)*8 + j][ci*16 + (l&15)]
extern "C" __global__ void k_make_bm(const float* __restrict__ emb,
                                     uint16_t* __restrict__ Bm) {
  __shared__ float ts[32][257];
  const int kc = blockIdx.x;                   // 0..255
  const int tid = threadIdx.x;
#pragma unroll
  for (int i = 0; i < 32; i++)
    ts[i][tid] = emb[(size_t)(kc * 32 + i) * HD + tid];
  __syncthreads();
#pragma unroll
  for (int c = 0; c < 4; c++) {
    int e = c * 256 + tid;                     // 16B-chunk index within kc
    int ci = e >> 6, l = e & 63;
    int g = l >> 4, col = ci * 16 + (l & 15);
    uint4 v;
    v.x = pack_bf2(ts[g * 8 + 0][col], ts[g * 8 + 1][col]);
    v.y = pack_bf2(ts[g * 8 + 2][col], ts[g * 8 + 3][col]);
    v.z = pack_bf2(ts[g * 8 + 4][col], ts[g * 8 + 5][col]);
    v.w = pack_bf2(ts[g * 8 + 6][col], ts[g * 8 + 7][col]);
    ((uint4*)Bm)[(size_t)kc * 1024 + e] = v;
  }
}

// ---------------------------------------------------------------- pack W:
// conv weight slices -> bf16 Wb[384][512]
extern "C" __global__ void k_pack_w(const float* __restrict__ k1,
                                    const float* __restrict__ k2,
                                    uint16_t* __restrict__ Wb) {
  int idx = blockIdx.x * 256 + threadIdx.x;    // 384*512 total
  int j = idx >> 9, k = idx & 511;
  float v;
  if (j < 128)      v = k1[j * 514 + 1 + k];
  else if (j < 256) v = k2[(j - 128) * 1028 + 515 + k];
  else              v = k2[(j - 256) * 1028 + 1 + k];
  Wb[idx] = f2bf(v);
}

// ---------------------------------------------------------------- GEMM:
// Rp[kblk][row][col] f32 partials; A f32 read directly (gathered rows),
// reg-staged -> bf16 frag-major LDS. B frag-major via global_load_lds.
// tile 32x256, BK=64, double-buffered. grid bid = mblk*4 + kblk
// (round-robin XCD: xcd = bid%8 -> kblk = xcd%4 fixed per XCD, B L2-resident)
extern "C" __global__ __launch_bounds__(256, 2)
void k_gemm(const float* __restrict__ A, const uint16_t* __restrict__ Bm,
            const int* __restrict__ bx, const int* __restrict__ by,
            float* __restrict__ Rp) {
  __shared__ __align__(16) uint16_t Af[2][2048];    // 4 KB x2  frag-major A
  __shared__ __align__(16) uint16_t Bf[2][16384];   // 32 KB x2 frag-major B
  __shared__ int ridx[32];
  const int tid = threadIdx.x;
  const int kblk = blockIdx.x & 3;
  const int mblk = blockIdx.x >> 2;
  if (tid < 32) {
    int gr = mblk * 32 + tid;
    ridx[tid] = (gr < BATCH) ? bx[gr] : by[gr - BATCH];
  }
  __syncthreads();
  const int wv = tid >> 6, l = tid & 63, g = l >> 4, l15 = l & 15;
  // A staging map: chunk e = tid -> kk=e>>7, ri=(e>>6)&1, row=ri*16+l15,
  // kloc=(kk*4+g)*8   (matches frag read below)
  const int s_row = ((tid >> 6) & 1) * 16 + l15;
  const int s_kloc = ((tid >> 7) * 4 + g) * 8;
  const float* aSrc = A + (size_t)ridx[s_row] * NN + kblk * KCH + s_kloc;
  const int aOff = tid * 8;                         // bf16 units
  const uint16_t* bBase = Bm + (size_t)kblk * 64 * 8192;

  f32x4 acc[2][4] = {};
  // ---- prologue: stage buf 0
  float4 a0 = *(const float4*)(aSrc);
  float4 a1 = *(const float4*)(aSrc + 4);
#pragma unroll
  for (int c = 0; c < 8; c++)
    gld_lds16(bBase + (size_t)(c * 256 + tid) * 8,
              &Bf[0][(size_t)(c * 256 + wv * 64) * 8]);
  {
    uint4 av;
    av.x = pack_bf2(a0.x, a0.y); av.y = pack_bf2(a0.z, a0.w);
    av.z = pack_bf2(a1.x, a1.y); av.w = pack_bf2(a1.z, a1.w);
    *(uint4*)&Af[0][aOff] = av;
  }
  asm volatile("s_waitcnt vmcnt(0)" ::: "memory");
  __syncthreads();

  for (int ks = 0; ks < KCH / 64 - 1; ks++) {
    const int cur = ks & 1, nxt = cur ^ 1;
    // ---- prefetch ks+1 (A->regs, B->LDS[nxt])
    const float* aS = aSrc + (ks + 1) * 64;
    a0 = *(const float4*)(aS);
    a1 = *(const float4*)(aS + 4);
    const uint16_t* bS = bBase + (size_t)(ks + 1) * 2 * 8192;
#pragma unroll
    for (int c = 0; c < 8; c++)
      gld_lds16(bS + (size_t)(c * 256 + tid) * 8,
                &Bf[nxt][(size_t)(c * 256 + wv * 64) * 8]);
    // ---- compute buf[cur]
    bf16x8 af[2][2], bfr[2][4];
#pragma unroll
    for (int kk = 0; kk < 2; kk++)
#pragma unroll
      for (int ri = 0; ri < 2; ri++)
        af[kk][ri] = *(const bf16x8*)&Af[cur][(size_t)((kk * 2 + ri) * 64 + l) * 8];
#pragma unroll
    for (int kk = 0; kk < 2; kk++)
#pragma unroll
      for (int ci = 0; ci < 4; ci++)
        bfr[kk][ci] = *(const bf16x8*)&Bf[cur][(size_t)(kk * 1024 + (wv * 4 + ci) * 64 + l) * 8];
#pragma unroll
    for (int kk = 0; kk < 2; kk++)
#pragma unroll
      for (int ri = 0; ri < 2; ri++)
#pragma unroll
        for (int ci = 0; ci < 4; ci++)
          acc[ri][ci] = __builtin_amdgcn_mfma_f32_16x16x32_bf16(
              af[kk][ri], bfr[kk][ci], acc[ri][ci], 0, 0, 0);
    // ---- write-late A stage into nxt (a0/a1 auto-waited by compiler)
    asm volatile("s_waitcnt vmcnt(8)" ::: "memory");
    {
      uint4 av;
      av.x = pack_bf2(a0.x, a0.y); av.y = pack_bf2(a0.z, a0.w);
      av.z = pack_bf2(a1.x, a1.y); av.w = pack_bf2(a1.z, a1.w);
      *(uint4*)&Af[nxt][aOff] = av;
    }
    asm volatile("s_waitcnt vmcnt(0)" ::: "memory");
    __syncthreads();
  }
  // ---- final compute (buf 1)
  {
    const int cur = (KCH / 64 - 1) & 1;
    bf16x8 af[2][2], bfr[2][4];
#pragma unroll
    for (int kk = 0; kk < 2; kk++)
#pragma unroll
      for (int ri = 0; ri < 2; ri++)
        af[kk][ri] = *(const bf16x8*)&Af[cur][(size_t)((kk * 2 + ri) * 64 + l) * 8];
#pragma unroll
    for (int kk = 0; kk < 2; kk++)
#pragma unroll
      for (int ci = 0; ci < 4; ci++)
        bfr[kk][ci] = *(const bf16x8*)&Bf[cur][(size_t)(kk * 1024 + (wv * 4 + ci) * 64 + l) * 8];
#pragma unroll
    for (int kk = 0; kk < 2; kk++)
#pragma unroll
      for (int ri = 0; ri < 2; ri++)
#pragma unroll
        for (int ci = 0; ci < 4; ci++)
          acc[ri][ci] = __builtin_amdgcn_mfma_f32_16x16x32_bf16(
              af[kk][ri], bfr[kk][ci], acc[ri][ci], 0, 0, 0);
  }
  // ---- epilogue: C layout col=lane&15, row=(lane>>4)*4+reg
  float* Rpk = Rp + (size_t)kblk * (4096 * HD) + (size_t)(mblk * 32) * HD + wv * 64;
#pragma unroll
  for (int ri = 0; ri < 2; ri++)
#pragma unroll
    for (int ci = 0; ci < 4; ci++)
#pragma unroll
      for (int r = 0; r < 4; r++)
        Rpk[(size_t)(ri * 16 + g * 4 + r) * HD + ci * 16 + l15] = acc[ri][ci][r];
}

// ---------------------------------------------------------------- tail:
// 4 batch elems per block (512 blocks). t_s[512][4]: inner loop is one
// broadcast ds_read_b128 + 4 FMA per k. W streamed as bf16 from L2.
extern "C" __global__ __launch_bounds__(256, 2)
void k_tail(const float* __restrict__ Rp, const uint16_t* __restrict__ Wb,
            const float* __restrict__ b1, const float* __restrict__ b2,
            const float* __restrict__ dw, const float* __restrict__ dbias,
            float* __restrict__ out) {
  __shared__ float t_s[512][4];
  __shared__ float d_s[4][NDOT];
  const int tid = threadIdx.x;
  const int b0 = blockIdx.x * 4;
#pragma unroll
  for (int bi = 0; bi < 4; bi++) {
    const int b = b0 + bi;
    float rq = 0.f, ra = 0.f;
#pragma unroll
    for (int p = 0; p < KSPLIT; p++) {
      rq += Rp[((size_t)p * 4096 + b) * HD + tid];
      ra += Rp[((size_t)p * 4096 + BATCH + b) * HD + tid];
    }
    float d = rq - ra;
    t_s[tid][bi] = d * d;          // (rQ-rA)^2
    t_s[256 + tid][bi] = rq * ra;  // rQ*rA
  }
  __syncthreads();
  {
    f32x4 acc = {0.f, 0.f, 0.f, 0.f};
    const uint16_t* wr = Wb + (size_t)tid * 512;
    for (int k = 0; k < 512; k += 8) {
      uint4 w8 = *(const uint4*)(wr + k);
      float w[8];
      w[0] = bf_lo(w8.x); w[1] = bf_hi(w8.x);
      w[2] = bf_lo(w8.y); w[3] = bf_hi(w8.y);
      w[4] = bf_lo(w8.z); w[5] = bf_hi(w8.z);
      w[6] = bf_lo(w8.w); w[7] = bf_hi(w8.w);
#pragma unroll
      for (int j = 0; j < 8; j++) {
        f32x4 tv = *(const f32x4*)&t_s[k + j][0];   // broadcast read
        acc += tv * w[j];
      }
    }
#pragma unroll
    for (int bi = 0; bi < 4; bi++) d_s[bi][tid] = acc[bi];
  }
  if (tid < 128) {
    f32x4 acc = {0.f, 0.f, 0.f, 0.f};
    const uint16_t* wr = Wb + (size_t)(256 + tid) * 512;
    for (int k = 0; k < 512; k += 8) {
      uint4 w8 = *(const uint4*)(wr + k);
      float w[8];
      w[0] = bf_lo(w8.x); w[1] = bf_hi(w8.x);
      w[2] = bf_lo(w8.y); w[3] = bf_hi(w8.y);
      w[4] = bf_lo(w8.z); w[5] = bf_hi(w8.z);
      w[6] = bf_lo(w8.w); w[7] = bf_hi(w8.w);
#pragma unroll
      for (int j = 0; j < 8; j++) {
        f32x4 tv = *(const f32x4*)&t_s[k + j][0];
        acc += tv * w[j];
      }
    }
#pragma unroll
    for (int bi = 0; bi < 4; bi++) d_s[bi][256 + tid] = acc[bi];
  }
  __syncthreads();
  // epilogue: bi = tid>>6, 64 lanes per batch elem, 2 cols each
  const int bi = tid >> 6, le = tid & 63;
  float s0 = 0.f, s1 = 0.f;
#pragma unroll
  for (int cc2 = 0; cc2 < 2; cc2++) {
    const int c = le + cc2 * 64;
    float d1 = d_s[bi][c], d2a = d_s[bi][128 + c], d2b = d_s[bi][256 + c];
    float bb1 = b1[c], bb2 = b2[c];
    float e1 = fmaxf(0.f, fmaxf(bb1, d1 + bb1));          // max-pool conv1
    float e2 = fmaxf(0.f, fmaxf(d2a + bb2, d2b + bb2));   // max-pool conv2
    s0 += e1 * (dw[c] + dw[256 + c]) + e2 * (dw[128 + c] + dw[384 + c]);
    s1 += e1 * (dw[512 + c] + dw[768 + c]) + e2 * (dw[640 + c] + dw[896 + c]);
  }
#pragma unroll
  for (int off = 32; off >= 1; off >>= 1) {
    s0 += __shfl_xor(s0, off);
    s1 += __shfl_xor(s1, off);
  }
  if (le == 0) {
    s0 += dbias[0]; s1 += dbias[1];
    float m = fmaxf(s0, s1);
    float lse = m + logf(expf(s0 - m) + expf(s1 - m));
    out[(b0 + bi) * 2] = s0 - lse;
    out[(b0 + bi) * 2 + 1] = s1 - lse;
  }
}

// ---------------------------------------------------------------- launch
extern "C" void kernel_launch(void* const* d_in, const int* in_sizes, int n_in,
                              void* d_out, int out_size, void* d_ws, size_t ws_size,
                              hipStream_t stream) {
  const float* emb = (const float*)d_in[0];
  const float* A   = (const float*)d_in[1];
  const float* k1  = (const float*)d_in[2];
  const float* b1  = (const float*)d_in[3];
  const float* k2  = (const float*)d_in[4];
  const float* b2  = (const float*)d_in[5];
  const float* dw  = (const float*)d_in[6];
  const float* dbi = (const float*)d_in[7];
  const int* bx = (const int*)d_in[8];
  const int* by = (const int*)d_in[9];
  float* out = (float*)d_out;
  char* ws = (char*)d_ws;
  // ws layout: [0,4M) Bm bf16 ; [4M,4.5M) Wb bf16 ; [8M,24M) Rp f32
  uint16_t* Bm = (uint16_t*)ws;
  uint16_t* Wb = (uint16_t*)(ws + (4u << 20));
  float* Rp = (float*)(ws + (8u << 20));

  k_make_bm<<<256, 256, 0, stream>>>(emb, Bm);
  k_pack_w<<<(NDOT * 512) / 256, 256, 0, stream>>>(k1, k2, Wb);
  k_gemm<<<128 * KSPLIT, 256, 0, stream>>>(A, Bm, bx, by, Rp);
  k_tail<<<BATCH / 4, 256, 0, stream>>>(Rp, Wb, b1, b2, dw, dbi, out);
}

// Round 4
// 80.077 us; speedup vs baseline: 2.1481x; 1.2509x over previous
//
#include <hip/hip_runtime.h>
#include <stdint.h>
#include <math.h>

// Problem constants
#define NN 8192     // graph nodes == GEMM K
#define HD 256      // hidden dim == GEMM N
#define BATCH 2048
#define KSPLIT 8
#define KCH (NN / KSPLIT)   // 1024 K per kblk

typedef __attribute__((ext_vector_type(8))) short bf16x8;
typedef __attribute__((ext_vector_type(4))) float f32x4;

static __device__ __forceinline__ uint16_t f2bf(float x) {
  union { float f; uint32_t u; } a; a.f = x;
  return (uint16_t)((a.u + 0x7FFFu + ((a.u >> 16) & 1u)) >> 16);
}
static __device__ __forceinline__ uint32_t pack_bf2(float x, float y) {
  union { float f; uint32_t u; } a, b; a.f = x; b.f = y;
  uint32_t ua = a.u + 0x7FFFu + ((a.u >> 16) & 1u);
  uint32_t ub = b.u + 0x7FFFu + ((b.u >> 16) & 1u);
  return (ua >> 16) | (ub & 0xFFFF0000u);
}

// ---------------------------------------------------------------- make Bm:
// emb[8192][256] f32 -> Bm frag-major bf16:
// chunk (kc, ci, l): Bm[((kc*16+ci)*64+l)*8 + j] = emb[kc*32+(l>>4)*8+j][ci*16+(l&15)]
extern "C" __global__ void k_make_bm(const float* __restrict__ emb,
                                     uint16_t* __restrict__ Bm) {
  __shared__ float ts[32][257];
  const int kc = blockIdx.x;                   // 0..255
  const int tid = threadIdx.x;
#pragma unroll
  for (int i = 0; i < 32; i++)
    ts[i][tid] = emb[(size_t)(kc * 32 + i) * HD + tid];
  __syncthreads();
#pragma unroll
  for (int c = 0; c < 4; c++) {
    int e = c * 256 + tid;                     // chunk index within kc (0..1023)
    int ci = e >> 6, l = e & 63;
    int g = l >> 4, col = ci * 16 + (l & 15);
    uint4 v;
    v.x = pack_bf2(ts[g * 8 + 0][col], ts[g * 8 + 1][col]);
    v.y = pack_bf2(ts[g * 8 + 2][col], ts[g * 8 + 3][col]);
    v.z = pack_bf2(ts[g * 8 + 4][col], ts[g * 8 + 5][col]);
    v.w = pack_bf2(ts[g * 8 + 6][col], ts[g * 8 + 7][col]);
    ((uint4*)Bm)[(size_t)kc * 1024 + e] = v;
  }
}

// ---------------------------------------------------------------- pack Wm:
// conv weight slices -> frag-major bf16 Wm, chunks (kc 0..15, ci 0..23, l 0..63)
extern "C" __global__ void k_pack_wm(const float* __restrict__ k1,
                                     const float* __restrict__ k2,
                                     uint16_t* __restrict__ Wm) {
  const int c = blockIdx.x * 256 + threadIdx.x;   // 0..24575
  const int lcl = c & 63;
  const int ci = (c >> 6) % 24;
  const int kc = c / (24 * 64);
  const int j = ci * 16 + (lcl & 15);     // output channel 0..383
  const int k0 = kc * 32 + ((lcl >> 4) << 3);
  float f[8];
#pragma unroll
  for (int jj = 0; jj < 8; jj++) {
    int k = k0 + jj;
    f[jj] = (j < 128) ? k1[j * 514 + 1 + k]
          : (j < 256) ? k2[(j - 128) * 1028 + 515 + k]
                      : k2[(j - 256) * 1028 + 1 + k];
  }
  uint4 v;
  v.x = pack_bf2(f[0], f[1]); v.y = pack_bf2(f[2], f[3]);
  v.z = pack_bf2(f[4], f[5]); v.w = pack_bf2(f[6], f[7]);
  *(uint4*)(Wm + (size_t)c * 8) = v;
}

// ---------------------------------------------------------------- GEMM:
// BM=128, 8 waves N-split (32 cols each). A f32 gathered-direct, reg->bf16->
// frag-major LDS (lane-linear, conflict-free). B frags wave-private,
// DIRECT global->reg from frag-major Bm (no LDS). 2-deep pipeline.
static __device__ __forceinline__ void compute_step(
    const uint16_t* afbase, int l, uint4 bc0, uint4 bc1, f32x4 acc[8][2]) {
  union { uint4 u; bf16x8 b; } c0, c1; c0.u = bc0; c1.u = bc1;
#pragma unroll
  for (int ri = 0; ri < 8; ri++) {
    bf16x8 af = *(const bf16x8*)(afbase + (ri * 64 + l) * 8);
    acc[ri][0] = __builtin_amdgcn_mfma_f32_16x16x32_bf16(af, c0.b, acc[ri][0], 0, 0, 0);
    acc[ri][1] = __builtin_amdgcn_mfma_f32_16x16x32_bf16(af, c1.b, acc[ri][1], 0, 0, 0);
  }
}

extern "C" __global__ __launch_bounds__(512, 2)
void k_gemm(const float* __restrict__ A, const uint16_t* __restrict__ Bm,
            const int* __restrict__ bx, const int* __restrict__ by,
            float* __restrict__ Rp) {
  __shared__ __align__(16) uint16_t Af[2][4096];   // 8 KB each, frag-major
  const int tid = threadIdx.x;
  const int kblk = blockIdx.x & 7;                 // XCD-pinned K-split
  const int mblk = blockIdx.x >> 3;
  const int wv = tid >> 6, l = tid & 63, g = l >> 4, l15 = l & 15;

  // A staging: thread t owns frag chunk t: row = (t>>6)*16 + (t&15),
  // k-seg = ((t>>4)&3)*8  (matches frag-read layout exactly)
  const int srow = ((tid >> 6) << 4) | (tid & 15);
  const int gr = mblk * 128 + srow;
  const int arow = (gr < BATCH) ? bx[gr] : by[gr - BATCH];
  const float* aSrc = A + (size_t)arow * NN + kblk * KCH + ((tid >> 4) & 3) * 8;
  // B: wave wv owns cols wv*32..+31 -> frags ci = wv*2, wv*2+1
  const uint16_t* bBase = Bm + (((size_t)(kblk * 32) * 16 + wv * 2) * 64 + l) * 8;

  f32x4 acc[8][2] = {};
  float4 a0a, a0b, a1a, a1b;       // A pipeline slots (even/odd)
  uint4 b0c0, b0c1, b1c0, b1c1;    // B pipeline slots

#define LD4(p) (*(const float4*)(p))
#define LDB(i, cj) (*(const uint4*)(bBase + (size_t)(i) * 8192 + (cj) * 512))
#define ISSUE_A0(i) { a0a = LD4(aSrc + (i) * 32); a0b = LD4(aSrc + (i) * 32 + 4); }
#define ISSUE_A1(i) { a1a = LD4(aSrc + (i) * 32); a1b = LD4(aSrc + (i) * 32 + 4); }
#define ISSUE_B0(i) { b0c0 = LDB(i, 0); b0c1 = LDB(i, 1); }
#define ISSUE_B1(i) { b1c0 = LDB(i, 0); b1c1 = LDB(i, 1); }
#define PACK_A(va, vb, buf) { uint4 v; \
    v.x = pack_bf2(va.x, va.y); v.y = pack_bf2(va.z, va.w); \
    v.z = pack_bf2(vb.x, vb.y); v.w = pack_bf2(vb.z, vb.w); \
    *(uint4*)&Af[buf][tid * 8] = v; }

  // prologue: fill 2-deep
  ISSUE_A0(0); ISSUE_B0(0); ISSUE_A1(1); ISSUE_B1(1);
  PACK_A(a0a, a0b, 0);
  __syncthreads();

  for (int p = 0; p < 15; p++) {
    const int i = 2 * p;
    // even iter i: compute Af[0] x B(i)
    compute_step(Af[0], l, b0c0, b0c1, acc);
    ISSUE_A0(i + 2); ISSUE_B0(i + 2);
    PACK_A(a1a, a1b, 1);             // A(i+1) -> Af[1]
    __syncthreads();
    // odd iter i+1
    compute_step(Af[1], l, b1c0, b1c1, acc);
    ISSUE_A1(i + 3); ISSUE_B1(i + 3);
    PACK_A(a0a, a0b, 0);             // A(i+2) -> Af[0]
    __syncthreads();
  }
  // iter 30
  compute_step(Af[0], l, b0c0, b0c1, acc);
  PACK_A(a1a, a1b, 1);
  __syncthreads();
  // iter 31
  compute_step(Af[1], l, b1c0, b1c1, acc);

  // epilogue: C layout col=lane&15, row=(lane>>4)*4+reg
  float* Rpk = Rp + (size_t)kblk * (4096 * HD) + (size_t)(mblk * 128) * HD + wv * 32;
#pragma unroll
  for (int ri = 0; ri < 8; ri++)
#pragma unroll
    for (int cj = 0; cj < 2; cj++)
#pragma unroll
      for (int r = 0; r < 4; r++)
        Rpk[(size_t)(ri * 16 + g * 4 + r) * HD + cj * 16 + l15] = acc[ri][cj][r];
#undef LD4
#undef LDB
#undef ISSUE_A0
#undef ISSUE_A1
#undef ISSUE_B0
#undef ISSUE_B1
#undef PACK_A
}

// ---------------------------------------------------------------- tbuild:
// pure streaming: reduce 8 Rp partials -> t = [d^2, rq*ra] -> bf16 Tb[2048][512]
extern "C" __global__ __launch_bounds__(256, 4)
void k_tbuild(const float* __restrict__ Rp, uint16_t* __restrict__ Tb) {
  const int tid = threadIdx.x;
  const int b0 = blockIdx.x * 8;
#pragma unroll 2
  for (int bi = 0; bi < 8; bi++) {
    const int b = b0 + bi;
    float rq = 0.f, ra = 0.f;
#pragma unroll
    for (int p = 0; p < KSPLIT; p++) {
      rq += Rp[((size_t)p * 4096 + b) * HD + tid];
      ra += Rp[((size_t)p * 4096 + BATCH + b) * HD + tid];
    }
    float d = rq - ra;
    Tb[(size_t)b * 512 + tid] = f2bf(d * d);
    Tb[(size_t)b * 512 + 256 + tid] = f2bf(rq * ra);
  }
}

// ---------------------------------------------------------------- tgemm:
// C[2048][384] = Tb x Wm^T via MFMA, frags direct from global (L2-resident),
// no LDS in main loop; fused enc/score/log-softmax epilogue.
extern "C" __global__ __launch_bounds__(256, 2)
void k_tgemm(const uint16_t* __restrict__ Tb, const uint16_t* __restrict__ Wm,
             const float* __restrict__ b1, const float* __restrict__ b2,
             const float* __restrict__ dw, const float* __restrict__ dbias,
             float* __restrict__ out) {
  __shared__ float Cl[32][388];
  __shared__ float coef[6][128];
  const int tid = threadIdx.x;
  const int b0 = blockIdx.x * 32;
  const int wv = tid >> 6, l = tid & 63, g = l >> 4, l15 = l & 15;
  if (tid < 128) {
    coef[0][tid] = dw[tid] + dw[256 + tid];
    coef[1][tid] = dw[128 + tid] + dw[384 + tid];
    coef[2][tid] = dw[512 + tid] + dw[768 + tid];
    coef[3][tid] = dw[640 + tid] + dw[896 + tid];
    coef[4][tid] = b1[tid];
    coef[5][tid] = b2[tid];
  }
  f32x4 acc[2][6] = {};
  const uint16_t* aR0 = Tb + (size_t)(b0 + l15) * 512 + g * 8;
  const uint16_t* aR1 = Tb + (size_t)(b0 + 16 + l15) * 512 + g * 8;
  const uint16_t* wB = Wm + ((size_t)(wv * 6) * 64 + l) * 8;
#pragma unroll 2
  for (int kc = 0; kc < 16; kc++) {
    bf16x8 a0 = *(const bf16x8*)(aR0 + kc * 32);
    bf16x8 a1 = *(const bf16x8*)(aR1 + kc * 32);
#pragma unroll
    for (int ci = 0; ci < 6; ci++) {
      bf16x8 w = *(const bf16x8*)(wB + (size_t)kc * 24 * 512 + ci * 512);
      acc[0][ci] = __builtin_amdgcn_mfma_f32_16x16x32_bf16(a0, w, acc[0][ci], 0, 0, 0);
      acc[1][ci] = __builtin_amdgcn_mfma_f32_16x16x32_bf16(a1, w, acc[1][ci], 0, 0, 0);
    }
  }
#pragma unroll
  for (int ri = 0; ri < 2; ri++)
#pragma unroll
    for (int ci = 0; ci < 6; ci++)
#pragma unroll
      for (int r = 0; r < 4; r++)
        Cl[ri * 16 + g * 4 + r][wv * 96 + ci * 16 + l15] = acc[ri][ci][r];
  __syncthreads();
  const int r = tid >> 3, sub = tid & 7;
  float s0 = 0.f, s1 = 0.f;
#pragma unroll
  for (int cc = 0; cc < 16; cc++) {
    const int c = sub * 16 + cc;
    float d1 = Cl[r][c], d2a = Cl[r][128 + c], d2b = Cl[r][256 + c];
    float bb1 = coef[4][c], bb2 = coef[5][c];
    float e1 = fmaxf(0.f, fmaxf(bb1, d1 + bb1));          // max-pool conv1
    float e2 = fmaxf(0.f, fmaxf(d2a + bb2, d2b + bb2));   // max-pool conv2
    s0 += e1 * coef[0][c] + e2 * coef[1][c];
    s1 += e1 * coef[2][c] + e2 * coef[3][c];
  }
  s0 += __shfl_xor(s0, 1); s1 += __shfl_xor(s1, 1);
  s0 += __shfl_xor(s0, 2); s1 += __shfl_xor(s1, 2);
  s0 += __shfl_xor(s0, 4); s1 += __shfl_xor(s1, 4);
  if (sub == 0) {
    s0 += dbias[0]; s1 += dbias[1];
    float m = fmaxf(s0, s1);
    float lse = m + logf(expf(s0 - m) + expf(s1 - m));
    out[(b0 + r) * 2] = s0 - lse;
    out[(b0 + r) * 2 + 1] = s1 - lse;
  }
}

// ---------------------------------------------------------------- launch
extern "C" void kernel_launch(void* const* d_in, const int* in_sizes, int n_in,
                              void* d_out, int out_size, void* d_ws, size_t ws_size,
                              hipStream_t stream) {
  const float* emb = (const float*)d_in[0];
  const float* A   = (const float*)d_in[1];
  const float* k1  = (const float*)d_in[2];
  const float* b1  = (const float*)d_in[3];
  const float* k2  = (const float*)d_in[4];
  const float* b2  = (const float*)d_in[5];
  const float* dw  = (const float*)d_in[6];
  const float* dbi = (const float*)d_in[7];
  const int* bx = (const int*)d_in[8];
  const int* by = (const int*)d_in[9];
  float* out = (float*)d_out;
  char* ws = (char*)d_ws;
  // ws: [0,4M) Bm ; [4M,+768K) Wm ; [5M,7M) Tb ; [8M,40M) Rp
  uint16_t* Bm = (uint16_t*)ws;
  uint16_t* Wm = (uint16_t*)(ws + (4u << 20));
  uint16_t* Tb = (uint16_t*)(ws + (5u << 20));
  float* Rp = (float*)(ws + (8u << 20));

  k_make_bm<<<256, 256, 0, stream>>>(emb, Bm);
  k_pack_wm<<<96, 256, 0, stream>>>(k1, k2, Wm);
  k_gemm<<<32 * KSPLIT, 512, 0, stream>>>(A, Bm, bx, by, Rp);
  k_tbuild<<<256, 256, 0, stream>>>(Rp, Tb);
  k_tgemm<<<64, 256, 0, stream>>>(Tb, Wm, b1, b2, dw, dbi, out);
}

// Round 5
// 66.188 us; speedup vs baseline: 2.5989x; 1.2098x over previous
//
#include <hip/hip_runtime.h>
#include <stdint.h>
#include <math.h>

// Problem constants
#define NN 8192     // graph nodes == GEMM K
#define HD 256      // hidden dim == GEMM N
#define BATCH 2048
#define KSPLIT 8
#define KCH (NN / KSPLIT)   // 1024 K per kblk
#define STEPS (KCH / 64)    // 16 BK=64 steps

typedef __attribute__((ext_vector_type(8))) short bf16x8;
typedef __attribute__((ext_vector_type(4))) float f32x4;

static __device__ __forceinline__ uint16_t f2bf(float x) {
  union { float f; uint32_t u; } a; a.f = x;
  return (uint16_t)((a.u + 0x7FFFu + ((a.u >> 16) & 1u)) >> 16);
}
static __device__ __forceinline__ uint32_t pack_bf2(float x, float y) {
  union { float f; uint32_t u; } a, b; a.f = x; b.f = y;
  uint32_t ua = a.u + 0x7FFFu + ((a.u >> 16) & 1u);
  uint32_t ub = b.u + 0x7FFFu + ((b.u >> 16) & 1u);
  return (ua >> 16) | (ub & 0xFFFF0000u);
}
static __device__ __forceinline__ float bf_lo(uint32_t u) {
  return __uint_as_float(u << 16);
}
static __device__ __forceinline__ float bf_hi(uint32_t u) {
  return __uint_as_float(u & 0xFFFF0000u);
}

// ---------------------------------------------------------------- prep:
// blocks 0..255:   emb[8192][256] f32 -> Bm frag-major bf16
//   Bm[((kc*16+ci)*64+l)*8+j] = emb[kc*32+(l>>4)*8+j][ci*16+(l&15)]
// blocks 256..351: conv weights -> Wm frag-major bf16 (kc 0..15, ci 0..23)
extern "C" __global__ void k_prep(const float* __restrict__ emb,
                                  const float* __restrict__ k1,
                                  const float* __restrict__ k2,
                                  uint16_t* __restrict__ Bm,
                                  uint16_t* __restrict__ Wm) {
  const int tid = threadIdx.x;
  if (blockIdx.x < 256) {
    __shared__ float ts[32][257];
    const int kc = blockIdx.x;
#pragma unroll
    for (int i = 0; i < 32; i++)
      ts[i][tid] = emb[(size_t)(kc * 32 + i) * HD + tid];
    __syncthreads();
#pragma unroll
    for (int c = 0; c < 4; c++) {
      int e = c * 256 + tid;
      int ci = e >> 6, l = e & 63;
      int g = l >> 4, col = ci * 16 + (l & 15);
      uint4 v;
      v.x = pack_bf2(ts[g * 8 + 0][col], ts[g * 8 + 1][col]);
      v.y = pack_bf2(ts[g * 8 + 2][col], ts[g * 8 + 3][col]);
      v.z = pack_bf2(ts[g * 8 + 4][col], ts[g * 8 + 5][col]);
      v.w = pack_bf2(ts[g * 8 + 6][col], ts[g * 8 + 7][col]);
      ((uint4*)Bm)[(size_t)kc * 1024 + e] = v;
    }
  } else {
    const int c = (blockIdx.x - 256) * 256 + tid;   // 0..24575
    const int lcl = c & 63;
    const int ci = (c >> 6) % 24;
    const int kc = c / (24 * 64);
    const int j = ci * 16 + (lcl & 15);
    const int k0 = kc * 32 + ((lcl >> 4) << 3);
    float f[8];
#pragma unroll
    for (int jj = 0; jj < 8; jj++) {
      int k = k0 + jj;
      f[jj] = (j < 128) ? k1[j * 514 + 1 + k]
            : (j < 256) ? k2[(j - 128) * 1028 + 515 + k]
                        : k2[(j - 256) * 1028 + 1 + k];
    }
    uint4 v;
    v.x = pack_bf2(f[0], f[1]); v.y = pack_bf2(f[2], f[3]);
    v.z = pack_bf2(f[4], f[5]); v.w = pack_bf2(f[6], f[7]);
    *(uint4*)(Wm + (size_t)c * 8) = v;
  }
}

// ---------------------------------------------------------------- GEMM:
// BM=64, 4 waves (64 cols each), BK=64, grid 512 (2 blocks/CU).
// A f32 gathered -> regs -> bf16 frag-major LDS. B direct global->reg from
// frag-major Bm (kblk XCD-pinned, L2-resident). Raw s_barrier + lgkmcnt-only
// wait so global prefetches stay in flight across barriers.
extern "C" __global__ __launch_bounds__(256, 2)
void k_gemm(const float* __restrict__ A, const uint16_t* __restrict__ Bm,
            const int* __restrict__ bx, const int* __restrict__ by,
            uint16_t* __restrict__ Rp) {
  __shared__ __align__(16) uint16_t Af[2][4096];   // 8 KB each: [kk*4+ri][l][8]
  const int tid = threadIdx.x;
  const int kblk = blockIdx.x & 7;                 // XCD = bid%8 == kblk
  const int mblk = blockIdx.x >> 3;
  const int wv = tid >> 6, l = tid & 63, g = l >> 4, l15 = l & 15;

  // A staging map: row = (tid>>6)*16 + (tid&15); s=(tid>>4)&3 -> 16 k-floats
  const int srow = ((tid >> 6) << 4) | (tid & 15);
  const int s = (tid >> 4) & 3;
  const int gr = mblk * 64 + srow;
  const int arow = (gr < BATCH) ? bx[gr] : by[gr - BATCH];
  const float* aSrc = A + (size_t)arow * NN + kblk * KCH + s * 16;
  // LDS dest (elems): kk=s>>1, g0=(s&1)*2, ri=tid>>6
  const int ldsE = ((s >> 1) * 4 + (tid >> 6)) * 512 + ((s & 1) * 2) * 128 + l15 * 8;
  // B: wave wv owns ci = wv*4+cj
  const uint16_t* bWave = Bm + ((size_t)(kblk * 32 * 16 + wv * 4) * 64 + l) * 8;

  f32x4 acc[4][4] = {};
  float4 aA0, aB0, aC0, aD0, aA1, aB1, aC1, aD1;   // A slots (16 floats each)
  bf16x8 b0[2][4], b1[2][4];                       // B slots

#define ISSUE_A0(i) { const float* p_ = aSrc + (i) * 64; \
    aA0 = *(const float4*)(p_); aB0 = *(const float4*)(p_ + 4); \
    aC0 = *(const float4*)(p_ + 8); aD0 = *(const float4*)(p_ + 12); }
#define ISSUE_A1(i) { const float* p_ = aSrc + (i) * 64; \
    aA1 = *(const float4*)(p_); aB1 = *(const float4*)(p_ + 4); \
    aC1 = *(const float4*)(p_ + 8); aD1 = *(const float4*)(p_ + 12); }
#define ISSUE_B(slot, i) { \
    _Pragma("unroll") for (int kk = 0; kk < 2; kk++) \
    _Pragma("unroll") for (int cj = 0; cj < 4; cj++) \
      slot[kk][cj] = *(const bf16x8*)(bWave + ((i) * 2 + kk) * 8192 + cj * 512); }
#define PACK_A(va, vb, vc, vd, buf) { uint4 v_; \
    v_.x = pack_bf2(va.x, va.y); v_.y = pack_bf2(va.z, va.w); \
    v_.z = pack_bf2(vb.x, vb.y); v_.w = pack_bf2(vb.z, vb.w); \
    *(uint4*)&Af[buf][ldsE] = v_; \
    v_.x = pack_bf2(vc.x, vc.y); v_.y = pack_bf2(vc.z, vc.w); \
    v_.z = pack_bf2(vd.x, vd.y); v_.w = pack_bf2(vd.z, vd.w); \
    *(uint4*)&Af[buf][ldsE + 128] = v_; }
#define COMPUTE(buf, bs) { \
    _Pragma("unroll") for (int kk = 0; kk < 2; kk++) { \
      _Pragma("unroll") for (int ri = 0; ri < 4; ri++) { \
        bf16x8 af = *(const bf16x8*)&Af[buf][((kk * 4 + ri) * 64 + l) * 8]; \
        _Pragma("unroll") for (int cj = 0; cj < 4; cj++) \
          acc[ri][cj] = __builtin_amdgcn_mfma_f32_16x16x32_bf16( \
              af, bs[kk][cj], acc[ri][cj], 0, 0, 0); } } }
#define SYNC { asm volatile("s_waitcnt lgkmcnt(0)" ::: "memory"); \
    __builtin_amdgcn_s_barrier(); }

  // prologue
  ISSUE_A0(0); ISSUE_B(b0, 0); ISSUE_A1(1); ISSUE_B(b1, 1);
  PACK_A(aA0, aB0, aC0, aD0, 0);
  SYNC;

  for (int p = 0; p < STEPS / 2 - 1; p++) {       // i = 0..13
    const int i = 2 * p;
    COMPUTE(0, b0);
    ISSUE_A0(i + 2); ISSUE_B(b0, i + 2);
    PACK_A(aA1, aB1, aC1, aD1, 1);
    SYNC;
    COMPUTE(1, b1);
    ISSUE_A1(i + 3); ISSUE_B(b1, i + 3);
    PACK_A(aA0, aB0, aC0, aD0, 0);
    SYNC;
  }
  COMPUTE(0, b0);                                 // i = 14
  PACK_A(aA1, aB1, aC1, aD1, 1);
  SYNC;
  COMPUTE(1, b1);                                 // i = 15

  // epilogue: row=ri*16+g*4+r, col=wv*64+cj*16+l15; pair cols via shfl_xor(1)
  uint16_t* Rpk = Rp + (size_t)kblk * (4096 * HD) + (size_t)(mblk * 64) * HD + wv * 64;
#pragma unroll
  for (int ri = 0; ri < 4; ri++)
#pragma unroll
    for (int cj = 0; cj < 4; cj++)
#pragma unroll
      for (int r = 0; r < 4; r++) {
        float v = acc[ri][cj][r];
        float vn = __shfl_xor(v, 1);
        if ((l15 & 1) == 0) {
          uint32_t pk = pack_bf2(v, vn);
          *(uint32_t*)(Rpk + (size_t)(ri * 16 + g * 4 + r) * HD + cj * 16 + l15) = pk;
        }
      }
#undef ISSUE_A0
#undef ISSUE_A1
#undef ISSUE_B
#undef PACK_A
#undef COMPUTE
#undef SYNC
}

// ---------------------------------------------------------------- tbuild:
// reduce 8 bf16 partials -> t = [d^2, rq*ra] -> bf16 Tb[2048][512]
extern "C" __global__ __launch_bounds__(256, 4)
void k_tbuild(const uint16_t* __restrict__ Rp, uint16_t* __restrict__ Tb) {
  const int tid = threadIdx.x;
  const int b = blockIdx.x * 8 + (tid >> 5);      // batch row
  const int c0 = (tid & 31) * 8;                  // 8 cols
  float rq[8] = {}, ra[8] = {};
#pragma unroll
  for (int p = 0; p < KSPLIT; p++) {
    uint4 q4 = *(const uint4*)(Rp + ((size_t)p * 4096 + b) * HD + c0);
    uint4 a4 = *(const uint4*)(Rp + ((size_t)p * 4096 + BATCH + b) * HD + c0);
    const uint32_t* qw = (const uint32_t*)&q4;
    const uint32_t* aw = (const uint32_t*)&a4;
#pragma unroll
    for (int w = 0; w < 4; w++) {
      rq[2 * w] += bf_lo(qw[w]); rq[2 * w + 1] += bf_hi(qw[w]);
      ra[2 * w] += bf_lo(aw[w]); ra[2 * w + 1] += bf_hi(aw[w]);
    }
  }
  uint32_t tq[4], ml[4];
#pragma unroll
  for (int w = 0; w < 4; w++) {
    float d0 = rq[2 * w] - ra[2 * w], d1 = rq[2 * w + 1] - ra[2 * w + 1];
    tq[w] = pack_bf2(d0 * d0, d1 * d1);
    ml[w] = pack_bf2(rq[2 * w] * ra[2 * w], rq[2 * w + 1] * ra[2 * w + 1]);
  }
  *(uint4*)(Tb + (size_t)b * 512 + c0) = *(uint4*)tq;
  *(uint4*)(Tb + (size_t)b * 512 + 256 + c0) = *(uint4*)ml;
}

// ---------------------------------------------------------------- tgemm:
// C[2048][384] = Tb x Wm^T via MFMA, frags direct from global (L2-resident);
// fused enc/score/log-softmax epilogue.
extern "C" __global__ __launch_bounds__(256, 2)
void k_tgemm(const uint16_t* __restrict__ Tb, const uint16_t* __restrict__ Wm,
             const float* __restrict__ b1, const float* __restrict__ b2,
             const float* __restrict__ dw, const float* __restrict__ dbias,
             float* __restrict__ out) {
  __shared__ float Cl[32][388];
  __shared__ float coef[6][128];
  const int tid = threadIdx.x;
  const int b0 = blockIdx.x * 32;
  const int wv = tid >> 6, l = tid & 63, g = l >> 4, l15 = l & 15;
  if (tid < 128) {
    coef[0][tid] = dw[tid] + dw[256 + tid];
    coef[1][tid] = dw[128 + tid] + dw[384 + tid];
    coef[2][tid] = dw[512 + tid] + dw[768 + tid];
    coef[3][tid] = dw[640 + tid] + dw[896 + tid];
    coef[4][tid] = b1[tid];
    coef[5][tid] = b2[tid];
  }
  f32x4 acc[2][6] = {};
  const uint16_t* aR0 = Tb + (size_t)(b0 + l15) * 512 + g * 8;
  const uint16_t* aR1 = Tb + (size_t)(b0 + 16 + l15) * 512 + g * 8;
  const uint16_t* wB = Wm + ((size_t)(wv * 6) * 64 + l) * 8;
#pragma unroll 2
  for (int kc = 0; kc < 16; kc++) {
    bf16x8 a0 = *(const bf16x8*)(aR0 + kc * 32);
    bf16x8 a1 = *(const bf16x8*)(aR1 + kc * 32);
#pragma unroll
    for (int ci = 0; ci < 6; ci++) {
      bf16x8 w = *(const bf16x8*)(wB + (size_t)kc * 24 * 512 + ci * 512);
      acc[0][ci] = __builtin_amdgcn_mfma_f32_16x16x32_bf16(a0, w, acc[0][ci], 0, 0, 0);
      acc[1][ci] = __builtin_amdgcn_mfma_f32_16x16x32_bf16(a1, w, acc[1][ci], 0, 0, 0);
    }
  }
#pragma unroll
  for (int ri = 0; ri < 2; ri++)
#pragma unroll
    for (int ci = 0; ci < 6; ci++)
#pragma unroll
      for (int r = 0; r < 4; r++)
        Cl[ri * 16 + g * 4 + r][wv * 96 + ci * 16 + l15] = acc[ri][ci][r];
  __syncthreads();
  const int r = tid >> 3, sub = tid & 7;
  float s0 = 0.f, s1 = 0.f;
#pragma unroll
  for (int cc = 0; cc < 16; cc++) {
    const int c = sub * 16 + cc;
    float d1 = Cl[r][c], d2a = Cl[r][128 + c], d2b = Cl[r][256 + c];
    float bb1 = coef[4][c], bb2 = coef[5][c];
    float e1 = fmaxf(0.f, fmaxf(bb1, d1 + bb1));
    float e2 = fmaxf(0.f, fmaxf(d2a + bb2, d2b + bb2));
    s0 += e1 * coef[0][c] + e2 * coef[1][c];
    s1 += e1 * coef[2][c] + e2 * coef[3][c];
  }
  s0 += __shfl_xor(s0, 1); s1 += __shfl_xor(s1, 1);
  s0 += __shfl_xor(s0, 2); s1 += __shfl_xor(s1, 2);
  s0 += __shfl_xor(s0, 4); s1 += __shfl_xor(s1, 4);
  if (sub == 0) {
    s0 += dbias[0]; s1 += dbias[1];
    float m = fmaxf(s0, s1);
    float lse = m + logf(expf(s0 - m) + expf(s1 - m));
    out[(b0 + r) * 2] = s0 - lse;
    out[(b0 + r) * 2 + 1] = s1 - lse;
  }
}

// ---------------------------------------------------------------- launch
extern "C" void kernel_launch(void* const* d_in, const int* in_sizes, int n_in,
                              void* d_out, int out_size, void* d_ws, size_t ws_size,
                              hipStream_t stream) {
  const float* emb = (const float*)d_in[0];
  const float* A   = (const float*)d_in[1];
  const float* k1  = (const float*)d_in[2];
  const float* b1  = (const float*)d_in[3];
  const float* k2  = (const float*)d_in[4];
  const float* b2  = (const float*)d_in[5];
  const float* dw  = (const float*)d_in[6];
  const float* dbi = (const float*)d_in[7];
  const int* bx = (const int*)d_in[8];
  const int* by = (const int*)d_in[9];
  float* out = (float*)d_out;
  char* ws = (char*)d_ws;
  // ws: [0,4M) Bm ; [4M,+768K) Wm ; [5M,7M) Tb ; [8M,24M) Rp bf16
  uint16_t* Bm = (uint16_t*)ws;
  uint16_t* Wm = (uint16_t*)(ws + (4u << 20));
  uint16_t* Tb = (uint16_t*)(ws + (5u << 20));
  uint16_t* Rp = (uint16_t*)(ws + (8u << 20));

  k_prep<<<352, 256, 0, stream>>>(emb, k1, k2, Bm, Wm);
  k_gemm<<<64 * KSPLIT, 256, 0, stream>>>(A, Bm, bx, by, Rp);
  k_tbuild<<<256, 256, 0, stream>>>(Rp, Tb);
  k_tgemm<<<64, 256, 0, stream>>>(Tb, Wm, b1, b2, dw, dbi, out);
}

// Round 6
// 65.706 us; speedup vs baseline: 2.6179x; 1.0073x over previous
//
#include <hip/hip_runtime.h>
#include <stdint.h>
#include <math.h>

// Problem constants
#define NN 8192     // graph nodes == GEMM K
#define HD 256      // hidden dim == GEMM N
#define BATCH 2048
#define KSPLIT 8
#define KCH (NN / KSPLIT)   // 1024 K per kblk

typedef __attribute__((ext_vector_type(8))) short bf16x8;
typedef __attribute__((ext_vector_type(4))) float f32x4;

static __device__ __forceinline__ uint16_t f2bf(float x) {
  union { float f; uint32_t u; } a; a.f = x;
  return (uint16_t)((a.u + 0x7FFFu + ((a.u >> 16) & 1u)) >> 16);
}
static __device__ __forceinline__ uint32_t pack_bf2(float x, float y) {
  union { float f; uint32_t u; } a, b; a.f = x; b.f = y;
  uint32_t ua = a.u + 0x7FFFu + ((a.u >> 16) & 1u);
  uint32_t ub = b.u + 0x7FFFu + ((b.u >> 16) & 1u);
  return (ua >> 16) | (ub & 0xFFFF0000u);
}
static __device__ __forceinline__ float bf_lo(uint32_t u) {
  return __uint_as_float(u << 16);
}
static __device__ __forceinline__ float bf_hi(uint32_t u) {
  return __uint_as_float(u & 0xFFFF0000u);
}

// ---------------------------------------------------------------- prep:
// blocks 0..255:   emb[8192][256] f32 -> Bm frag-major bf16
//   Bm[((kc*16+ci)*64+l)*8+j] = emb[kc*32+(l>>4)*8+j][ci*16+(l&15)]
// blocks 256..351: conv weights -> Wm frag-major bf16 (kc 0..15, ci 0..23)
extern "C" __global__ void k_prep(const float* __restrict__ emb,
                                  const float* __restrict__ k1,
                                  const float* __restrict__ k2,
                                  uint16_t* __restrict__ Bm,
                                  uint16_t* __restrict__ Wm) {
  const int tid = threadIdx.x;
  if (blockIdx.x < 256) {
    __shared__ float ts[32][257];
    const int kc = blockIdx.x;
#pragma unroll
    for (int i = 0; i < 32; i++)
      ts[i][tid] = emb[(size_t)(kc * 32 + i) * HD + tid];
    __syncthreads();
#pragma unroll
    for (int c = 0; c < 4; c++) {
      int e = c * 256 + tid;
      int ci = e >> 6, l = e & 63;
      int g = l >> 4, col = ci * 16 + (l & 15);
      uint4 v;
      v.x = pack_bf2(ts[g * 8 + 0][col], ts[g * 8 + 1][col]);
      v.y = pack_bf2(ts[g * 8 + 2][col], ts[g * 8 + 3][col]);
      v.z = pack_bf2(ts[g * 8 + 4][col], ts[g * 8 + 5][col]);
      v.w = pack_bf2(ts[g * 8 + 6][col], ts[g * 8 + 7][col]);
      ((uint4*)Bm)[(size_t)kc * 1024 + e] = v;
    }
  } else {
    const int c = (blockIdx.x - 256) * 256 + tid;   // 0..24575
    const int lcl = c & 63;
    const int ci = (c >> 6) % 24;
    const int kc = c / (24 * 64);
    const int j = ci * 16 + (lcl & 15);
    const int k0 = kc * 32 + ((lcl >> 4) << 3);
    float f[8];
#pragma unroll
    for (int jj = 0; jj < 8; jj++) {
      int k = k0 + jj;
      f[jj] = (j < 128) ? k1[j * 514 + 1 + k]
            : (j < 256) ? k2[(j - 128) * 1028 + 515 + k]
                        : k2[(j - 256) * 1028 + 1 + k];
    }
    uint4 v;
    v.x = pack_bf2(f[0], f[1]); v.y = pack_bf2(f[2], f[3]);
    v.z = pack_bf2(f[4], f[5]); v.w = pack_bf2(f[6], f[7]);
    *(uint4*)(Wm + (size_t)c * 8) = v;
  }
}

// ---------------------------------------------------------------- GEMM:
// BM=64, 4 waves (64 cols each), BK=64, grid 512 (2 blocks/CU).
// A f32 gathered, lane-contiguous coalesced (4 lanes/row -> full 64B lines),
// 3-deep A reg pipeline -> bf16 frag-major LDS. B direct global->reg from
// frag-major Bm (kblk XCD-pinned). Raw s_barrier + lgkmcnt-only waits.
// Epilogue: LDS exchange -> fully coalesced bf16 Rp stores.
extern "C" __global__ __launch_bounds__(256, 2)
void k_gemm(const float* __restrict__ A, const uint16_t* __restrict__ Bm,
            const int* __restrict__ bx, const int* __restrict__ by,
            uint16_t* __restrict__ Rp) {
  __shared__ __align__(16) uint16_t shb[16384];    // Af[2][4096] | Ct[64][256]
  const int tid = threadIdx.x;
  const int kblk = blockIdx.x & 7;                 // XCD = bid%8 == kblk
  const int mblk = blockIdx.x >> 3;
  const int wv = tid >> 6, l = tid & 63, g = l >> 4, l15 = l & 15;

  // A gather: row = tid>>2 (4 threads per row, 16B each, contiguous)
  const int row = tid >> 2, q = tid & 3;
  const int gr = mblk * 64 + row;
  const int arow = (gr < BATCH) ? bx[gr] : by[gr - BATCH];
  const float* aSrc = A + (size_t)arow * NN + kblk * KCH + q * 4;
  // 4 LDS byte-offsets for the 4 float4 sub-loads (frag-major layout)
  int ldsO[4];
#pragma unroll
  for (int ii = 0; ii < 4; ii++) {
    int k0 = q * 4 + 16 * ii;
    int chunk = ((k0 >> 5) * 4 + (row >> 4)) * 64 + ((k0 >> 3) & 3) * 16 + (row & 15);
    ldsO[ii] = chunk * 16 + (k0 & 7) * 2;
  }
  const int ldsO0 = ldsO[0], ldsO1 = ldsO[1], ldsO2 = ldsO[2], ldsO3 = ldsO[3];
  // B: wave wv owns ci = wv*4+cj
  const uint16_t* bWave = Bm + ((size_t)(kblk * 32 * 16 + wv * 4) * 64 + l) * 8;

  f32x4 acc[4][4] = {};
  float4 a0a, a0b, a0c, a0d, a1a, a1b, a1c, a1d, a2a, a2b, a2c, a2d;
  bf16x8 b0[2][4], b1[2][4];

#define ISSUE_A0(i) { const float* p_ = aSrc + (i) * 64; \
    a0a = *(const float4*)(p_);      a0b = *(const float4*)(p_ + 16); \
    a0c = *(const float4*)(p_ + 32); a0d = *(const float4*)(p_ + 48); }
#define ISSUE_A1(i) { const float* p_ = aSrc + (i) * 64; \
    a1a = *(const float4*)(p_);      a1b = *(const float4*)(p_ + 16); \
    a1c = *(const float4*)(p_ + 32); a1d = *(const float4*)(p_ + 48); }
#define ISSUE_A2(i) { const float* p_ = aSrc + (i) * 64; \
    a2a = *(const float4*)(p_);      a2b = *(const float4*)(p_ + 16); \
    a2c = *(const float4*)(p_ + 32); a2d = *(const float4*)(p_ + 48); }
#define ISSUE_B0(i) { \
    _Pragma("unroll") for (int kk = 0; kk < 2; kk++) \
    _Pragma("unroll") for (int cj = 0; cj < 4; cj++) \
      b0[kk][cj] = *(const bf16x8*)(bWave + ((i) * 2 + kk) * 8192 + cj * 512); }
#define ISSUE_B1(i) { \
    _Pragma("unroll") for (int kk = 0; kk < 2; kk++) \
    _Pragma("unroll") for (int cj = 0; cj < 4; cj++) \
      b1[kk][cj] = *(const bf16x8*)(bWave + ((i) * 2 + kk) * 8192 + cj * 512); }
#define PK1(va, off, buf) { uint2 v_; \
    v_.x = pack_bf2(va.x, va.y); v_.y = pack_bf2(va.z, va.w); \
    *(uint2*)((char*)shb + (buf) * 8192 + (off)) = v_; }
#define PACK_A0(buf) { PK1(a0a, ldsO0, buf); PK1(a0b, ldsO1, buf); \
                       PK1(a0c, ldsO2, buf); PK1(a0d, ldsO3, buf); }
#define PACK_A1(buf) { PK1(a1a, ldsO0, buf); PK1(a1b, ldsO1, buf); \
                       PK1(a1c, ldsO2, buf); PK1(a1d, ldsO3, buf); }
#define PACK_A2(buf) { PK1(a2a, ldsO0, buf); PK1(a2b, ldsO1, buf); \
                       PK1(a2c, ldsO2, buf); PK1(a2d, ldsO3, buf); }
#define COMPUTE(buf, bs) { \
    _Pragma("unroll") for (int kk = 0; kk < 2; kk++) { \
      _Pragma("unroll") for (int ri = 0; ri < 4; ri++) { \
        bf16x8 af = *(const bf16x8*)((char*)shb + (buf) * 8192 + \
                                     ((kk * 4 + ri) * 64 + l) * 16); \
        _Pragma("unroll") for (int cj = 0; cj < 4; cj++) \
          acc[ri][cj] = __builtin_amdgcn_mfma_f32_16x16x32_bf16( \
              af, bs[kk][cj], acc[ri][cj], 0, 0, 0); } } }
#define SYNC_ { asm volatile("s_waitcnt lgkmcnt(0)" ::: "memory"); \
    __builtin_amdgcn_s_barrier(); asm volatile("" ::: "memory"); }

  // prologue: A 3-deep, B 2-deep
  ISSUE_A0(0); ISSUE_A1(1); ISSUE_A2(2);
  ISSUE_B0(0); ISSUE_B1(1);
  PACK_A0(0);
  SYNC_;

#define SIX(base) \
  { COMPUTE(0, b0); ISSUE_A0((base) + 3); ISSUE_B0((base) + 2); PACK_A1(1); SYNC_; } \
  { COMPUTE(1, b1); ISSUE_A1((base) + 4); ISSUE_B1((base) + 3); PACK_A2(0); SYNC_; } \
  { COMPUTE(0, b0); ISSUE_A2((base) + 5); ISSUE_B0((base) + 4); PACK_A0(1); SYNC_; } \
  { COMPUTE(1, b1); ISSUE_A0((base) + 6); ISSUE_B1((base) + 5); PACK_A1(0); SYNC_; } \
  { COMPUTE(0, b0); ISSUE_A1((base) + 7); ISSUE_B0((base) + 6); PACK_A2(1); SYNC_; } \
  { COMPUTE(1, b1); ISSUE_A2((base) + 8); ISSUE_B1((base) + 7); PACK_A0(0); SYNC_; }

  SIX(0);
  SIX(6);
  // tail: i = 12..15
  { COMPUTE(0, b0); ISSUE_A0(15); ISSUE_B0(14); PACK_A1(1); SYNC_; }
  { COMPUTE(1, b1); ISSUE_B1(15); PACK_A2(0); SYNC_; }
  { COMPUTE(0, b0); PACK_A0(1); SYNC_; }
  { COMPUTE(1, b1); }
  SYNC_;                      // all LDS reads done; shb reusable as Ct

  // epilogue: pack col-pairs, exchange via LDS, coalesced global stores
  uint16_t* Ct = shb;
#pragma unroll
  for (int ri = 0; ri < 4; ri++)
#pragma unroll
    for (int cj = 0; cj < 4; cj++)
#pragma unroll
      for (int r = 0; r < 4; r++) {
        float v = acc[ri][cj][r];
        float vn = __shfl_xor(v, 1);
        if ((l15 & 1) == 0) {
          int row16 = ri * 16 + g * 4 + r;
          int col = wv * 64 + cj * 16 + l15;
          *(uint32_t*)(Ct + row16 * 256 + col) = pack_bf2(v, vn);
        }
      }
  __syncthreads();
  {
    const int row2 = tid >> 2, cb = (tid & 3) * 64;
    const uint4* src = (const uint4*)(Ct + row2 * 256 + cb);
    uint16_t* dst = Rp + ((size_t)kblk * 4096 + mblk * 64 + row2) * HD + cb;
    uint4 v0 = src[0], v1 = src[1], v2 = src[2], v3 = src[3];
    ((uint4*)dst)[0] = v0; ((uint4*)dst)[1] = v1;
    ((uint4*)dst)[2] = v2; ((uint4*)dst)[3] = v3;
  }
#undef ISSUE_A0
#undef ISSUE_A1
#undef ISSUE_A2
#undef ISSUE_B0
#undef ISSUE_B1
#undef PK1
#undef PACK_A0
#undef PACK_A1
#undef PACK_A2
#undef COMPUTE
#undef SYNC_
#undef SIX
}

// ---------------------------------------------------------------- tail:
// 256 blocks x 8 batch rows. Phase 1: reduce Rp -> t (bf16, frag-major LDS).
// Phase 2: MFMA vs Wm (L2-resident per XCD). Fused max-pool/score/log-softmax.
extern "C" __global__ __launch_bounds__(256, 2)
void k_tail(const uint16_t* __restrict__ Rp, const uint16_t* __restrict__ Wm,
            const float* __restrict__ b1, const float* __restrict__ b2,
            const float* __restrict__ dw, const float* __restrict__ dbias,
            float* __restrict__ out) {
  __shared__ __align__(16) uint16_t t_frag[16 * 64 * 8];   // 16 KB
  __shared__ float Cl[8][388];
  __shared__ float coef[6][128];
  const int tid = threadIdx.x;
  const int b0 = blockIdx.x * 8;
  const int wv = tid >> 6, l = tid & 63, g = l >> 4, l15 = l & 15;
  if (tid < 128) {
    coef[0][tid] = dw[tid] + dw[256 + tid];
    coef[1][tid] = dw[128 + tid] + dw[384 + tid];
    coef[2][tid] = dw[512 + tid] + dw[768 + tid];
    coef[3][tid] = dw[640 + tid] + dw[896 + tid];
    coef[4][tid] = b1[tid];
    coef[5][tid] = b2[tid];
  }
  // ---- phase 1: r = tid>>5 (0..7), c8 = (tid&31)*8 (8 cols of rq/ra)
  {
    const int r = tid >> 5, c8 = (tid & 31) * 8;
    float rq[8] = {}, ra[8] = {};
#pragma unroll
    for (int p = 0; p < KSPLIT; p++) {
      uint4 q4 = *(const uint4*)(Rp + ((size_t)p * 4096 + b0 + r) * HD + c8);
      uint4 a4 = *(const uint4*)(Rp + ((size_t)p * 4096 + BATCH + b0 + r) * HD + c8);
      const uint32_t* qw = (const uint32_t*)&q4;
      const uint32_t* aw = (const uint32_t*)&a4;
#pragma unroll
      for (int w = 0; w < 4; w++) {
        rq[2 * w] += bf_lo(qw[w]); rq[2 * w + 1] += bf_hi(qw[w]);
        ra[2 * w] += bf_lo(aw[w]); ra[2 * w + 1] += bf_hi(aw[w]);
      }
    }
    uint32_t tq[4], ml[4];
#pragma unroll
    for (int w = 0; w < 4; w++) {
      float d0 = rq[2 * w] - ra[2 * w], d1 = rq[2 * w + 1] - ra[2 * w + 1];
      tq[w] = pack_bf2(d0 * d0, d1 * d1);
      ml[w] = pack_bf2(rq[2 * w] * ra[2 * w], rq[2 * w + 1] * ra[2 * w + 1]);
    }
    // frag slot: kc = c>>5, gm = (c>>3)&3, lane = gm*16 + r
    const int kc1 = c8 >> 5, gm = (c8 >> 3) & 3;
    const int kc2 = 8 + kc1;
    *(uint4*)(t_frag + (kc1 * 64 + gm * 16 + r) * 8) = *(uint4*)tq;
    *(uint4*)(t_frag + (kc2 * 64 + gm * 16 + r) * 8) = *(uint4*)ml;
    // zero the unused rows 8..15 of both chunks
    uint4 z = {0, 0, 0, 0};
    *(uint4*)(t_frag + (kc1 * 64 + gm * 16 + 8 + r) * 8) = z;
    *(uint4*)(t_frag + (kc2 * 64 + gm * 16 + 8 + r) * 8) = z;
  }
  __syncthreads();
  // ---- phase 2: wave wv -> ci = wv*6 .. wv*6+5
  {
    f32x4 acc[6] = {};
    const uint16_t* wB = Wm + ((size_t)(wv * 6) * 64 + l) * 8;
#pragma unroll 2
    for (int kc = 0; kc < 16; kc++) {
      bf16x8 af = *(const bf16x8*)(t_frag + (kc * 64 + l) * 8);
#pragma unroll
      for (int ci = 0; ci < 6; ci++) {
        bf16x8 w = *(const bf16x8*)(wB + (size_t)kc * 12288 + ci * 512);
        acc[ci] = __builtin_amdgcn_mfma_f32_16x16x32_bf16(af, w, acc[ci], 0, 0, 0);
      }
    }
#pragma unroll
    for (int ci = 0; ci < 6; ci++)
#pragma unroll
      for (int r = 0; r < 4; r++) {
        int row16 = g * 4 + r;
        if (row16 < 8) Cl[row16][wv * 96 + ci * 16 + l15] = acc[ci][r];
      }
  }
  __syncthreads();
  // ---- epilogue: r = tid>>5, 32 lanes per row, 4 channels each
  {
    const int r = tid >> 5, ch0 = (tid & 31) * 4;
    float s0 = 0.f, s1 = 0.f;
#pragma unroll
    for (int cc = 0; cc < 4; cc++) {
      const int c = ch0 + cc;
      float d1 = Cl[r][c], d2a = Cl[r][128 + c], d2b = Cl[r][256 + c];
      float bb1 = coef[4][c], bb2 = coef[5][c];
      float e1 = fmaxf(0.f, fmaxf(bb1, d1 + bb1));          // max-pool conv1
      float e2 = fmaxf(0.f, fmaxf(d2a + bb2, d2b + bb2));   // max-pool conv2
      s0 += e1 * coef[0][c] + e2 * coef[1][c];
      s1 += e1 * coef[2][c] + e2 * coef[3][c];
    }
#pragma unroll
    for (int off = 16; off >= 1; off >>= 1) {
      s0 += __shfl_xor(s0, off, 32);
      s1 += __shfl_xor(s1, off, 32);
    }
    if ((tid & 31) == 0) {
      s0 += dbias[0]; s1 += dbias[1];
      float m = fmaxf(s0, s1);
      float lse = m + logf(expf(s0 - m) + expf(s1 - m));
      out[(b0 + r) * 2] = s0 - lse;
      out[(b0 + r) * 2 + 1] = s1 - lse;
    }
  }
}

// ---------------------------------------------------------------- launch
extern "C" void kernel_launch(void* const* d_in, const int* in_sizes, int n_in,
                              void* d_out, int out_size, void* d_ws, size_t ws_size,
                              hipStream_t stream) {
  const float* emb = (const float*)d_in[0];
  const float* A   = (const float*)d_in[1];
  const float* k1  = (const float*)d_in[2];
  const float* b1  = (const float*)d_in[3];
  const float* k2  = (const float*)d_in[4];
  const float* b2  = (const float*)d_in[5];
  const float* dw  = (const float*)d_in[6];
  const float* dbi = (const float*)d_in[7];
  const int* bx = (const int*)d_in[8];
  const int* by = (const int*)d_in[9];
  float* out = (float*)d_out;
  char* ws = (char*)d_ws;
  // ws: [0,4M) Bm ; [4M,+768K) Wm ; [8M,24M) Rp bf16
  uint16_t* Bm = (uint16_t*)ws;
  uint16_t* Wm = (uint16_t*)(ws + (4u << 20));
  uint16_t* Rp = (uint16_t*)(ws + (8u << 20));

  k_prep<<<352, 256, 0, stream>>>(emb, k1, k2, Bm, Wm);
  k_gemm<<<64 * KSPLIT, 256, 0, stream>>>(A, Bm, bx, by, Rp);
  k_tail<<<256, 256, 0, stream>>>(Rp, Wm, b1, b2, dw, dbi, out);
}